// Round 1
// baseline (323.644 us; speedup 1.0000x reference)
//
#include <hip/hip_runtime.h>

#define QMAXF 127.0f

typedef _Float16 f16x4 __attribute__((ext_vector_type(4)));
typedef float f32x4 __attribute__((ext_vector_type(4)));

union K2Smem {
  float xq[112][132];   // staged quantized x (integer values in f32), [hw][ci], pad 132 (==4 mod 32)
  float q2[128][113];   // FINAL: quantized y ints, [co][hw in 0..111], pad 113
  float comax[128];     // !FINAL: per-co max |y_int|
};

__global__ __launch_bounds__(256) void k0_prep(
    const float* __restrict__ actsf, const float* __restrict__ bnw,
    const float* __restrict__ bnb, const float* __restrict__ bnm,
    const float* __restrict__ bnv, const float* __restrict__ cw,
    float* __restrict__ wsf, float* __restrict__ scq, float* __restrict__ shq,
    unsigned short* __restrict__ wq, unsigned int* __restrict__ gmax1) {
  const int t = threadIdx.x;
  __shared__ float red[4];
  float scale, shift;
  {
#pragma clang fp contract(off)
    float inv = 1.0f / sqrtf(bnv[t] + 1e-5f);
    scale = bnw[t] * inv;
    float tmp = bnm[t] * scale;
    shift = bnb[t] - tmp;
  }
  float a = fabsf(scale);
  for (int o = 32; o > 0; o >>= 1) a = fmaxf(a, __shfl_xor(a, o));
  if ((t & 63) == 0) red[t >> 6] = a;
  __syncthreads();
  const float amax = fmaxf(fmaxf(red[0], red[1]), fmaxf(red[2], red[3]));
  const float bn_sf = amax / QMAXF;
  const float sq = fminf(fmaxf(rintf(scale / bn_sf), -128.f), 127.f) * bn_sf;
  const float bias_sf = bn_sf * actsf[0];
  const float sh_q = rintf(shift / bias_sf) * bias_sf;
  scq[t] = sq;
  shq[t] = sh_q;
  if (t == 0) *gmax1 = 0u;
  if (t < 128) {
    const float* wrow = cw + t * 256;
    float m = 0.f;
    for (int k = 0; k < 256; ++k) m = fmaxf(m, fabsf(wrow[k]));
    const float wsf_v = m / QMAXF;
    wsf[t] = wsf_v;
    for (int k = 0; k < 256; ++k) {
      float q = fminf(fmaxf(rintf(wrow[k] / wsf_v), -128.f), 127.f);
      _Float16 h = (_Float16)q;  // exact: small integer
      wq[t * 256 + k] = __builtin_bit_cast(unsigned short, h);
    }
  }
}

__global__ __launch_bounds__(256) void k1_maxz(
    const float* __restrict__ x, const float* __restrict__ scq,
    const float* __restrict__ shq, unsigned int* __restrict__ gmax1) {
  const int t = threadIdx.x;
  __shared__ float red[4];
  const float4* __restrict__ x4 = (const float4*)x;
  const unsigned total = 64u * 256u * 784u;  // float4 count
  float m = 0.f;  // max(relu(z)) == max(0, max z); m starts at 0
  for (unsigned i = blockIdx.x * 256u + t; i < total; i += gridDim.x * 256u) {
    const float4 v = x4[i];
    const unsigned row = i / 784u;  // n*256+ci
    const unsigned ci = row & 255u;
    const float s = scq[ci], sh = shq[ci];
    float z0, z1, z2, z3;
    {
#pragma clang fp contract(off)
      z0 = v.x * s + sh; z1 = v.y * s + sh; z2 = v.z * s + sh; z3 = v.w * s + sh;
    }
    m = fmaxf(m, fmaxf(fmaxf(z0, z1), fmaxf(z2, z3)));
  }
  for (int o = 32; o > 0; o >>= 1) m = fmaxf(m, __shfl_xor(m, o));
  if ((t & 63) == 0) red[t >> 6] = m;
  __syncthreads();
  if (t == 0) {
    float mm = fmaxf(fmaxf(red[0], red[1]), fmaxf(red[2], red[3]));
    atomicMax(gmax1, __float_as_uint(mm));  // mm >= 0, uint order == float order
  }
}

// Block tile: n fixed, 112 contiguous hw (2 image rows), K=256 (two 128-ci phases), N=128 co.
// A = W (16co x 16k), B = X^T (16k x 16hw)  ->  D rows = co, cols = hw.
template <bool FINAL>
__global__ __launch_bounds__(256, 2) void k2_gemm(
    const float* __restrict__ x, const float* __restrict__ scq,
    const float* __restrict__ shq, const unsigned short* __restrict__ wqu,
    const float* __restrict__ wsf, const unsigned int* __restrict__ gmax1,
    const float* __restrict__ sf2p, float* __restrict__ blockmax,
    float* __restrict__ out) {
  __shared__ K2Smem sm;
  __shared__ float red2[4];
  const int t = threadIdx.x;
  const int w = t >> 6;
  const int l = t & 63;
  const int blk = blockIdx.x;
  const int n = blk / 28;
  const int tt = blk - n * 28;                 // row-pair tile index (ho)
  const long xbase = (long)n * 802816 + tt * 112;
  const float sf1 = __uint_as_float(*gmax1) / QMAXF;
  const _Float16* __restrict__ wq16 = (const _Float16*)wqu;
  f32x4 acc[2][7];
#pragma unroll
  for (int ct = 0; ct < 2; ++ct)
#pragma unroll
    for (int ht = 0; ht < 7; ++ht) acc[ct][ht] = (f32x4){0.f, 0.f, 0.f, 0.f};

  for (int phase = 0; phase < 2; ++phase) {
    // ---- stage: 112 hw x 128 ci, quantize to integer-valued f32 ----
    for (int it = 0; it < 14; ++it) {
      const unsigned f = (unsigned)t + (unsigned)it * 256u;  // float4 slot in [0,3584)
      const unsigned ci_l = f / 28u;
      const unsigned hwp = (f - ci_l * 28u) * 4u;
      const int ci = phase * 128 + (int)ci_l;
      const float4 v = *(const float4*)(x + xbase + (long)ci * 3136 + hwp);
      const float s = scq[ci], sh = shq[ci];
      float z0, z1, z2, z3;
      {
#pragma clang fp contract(off)
        z0 = v.x * s + sh; z1 = v.y * s + sh; z2 = v.z * s + sh; z3 = v.w * s + sh;
      }
      z0 = fmaxf(z0, 0.f); z1 = fmaxf(z1, 0.f); z2 = fmaxf(z2, 0.f); z3 = fmaxf(z3, 0.f);
      sm.xq[hwp + 0][ci_l] = fminf(fmaxf(rintf(z0 / sf1), -128.f), 127.f);
      sm.xq[hwp + 1][ci_l] = fminf(fmaxf(rintf(z1 / sf1), -128.f), 127.f);
      sm.xq[hwp + 2][ci_l] = fminf(fmaxf(rintf(z2 / sf1), -128.f), 127.f);
      sm.xq[hwp + 3][ci_l] = fminf(fmaxf(rintf(z3 / sf1), -128.f), 127.f);
    }
    __syncthreads();
    const int kw = ((l >> 4) << 2);
#pragma unroll
    for (int ks = 0; ks < 8; ++ks) {
      const int kb = ks * 16 + kw;  // local k (0..127)
      f16x4 xf[7];
#pragma unroll
      for (int ht = 0; ht < 7; ++ht) {
        const float4 xv = *(const float4*)&sm.xq[ht * 16 + (l & 15)][kb];
        f16x4 h;
        h[0] = (_Float16)xv.x; h[1] = (_Float16)xv.y;
        h[2] = (_Float16)xv.z; h[3] = (_Float16)xv.w;
        xf[ht] = h;
      }
#pragma unroll
      for (int ct = 0; ct < 2; ++ct) {
        const int co = (w << 5) + (ct << 4) + (l & 15);
        const f16x4 wf = *(const f16x4*)(wq16 + co * 256 + phase * 128 + kb);
#pragma unroll
        for (int ht = 0; ht < 7; ++ht)
          acc[ct][ht] = __builtin_amdgcn_mfma_f32_16x16x16f16(wf, xf[ht], acc[ct][ht], 0, 0, 0);
      }
    }
    __syncthreads();
  }

  const int g = (l >> 4);
  if (!FINAL) {
    float im[2][4];
#pragma unroll
    for (int ct = 0; ct < 2; ++ct)
#pragma unroll
      for (int r = 0; r < 4; ++r) {
        float v = 0.f;
#pragma unroll
        for (int ht = 0; ht < 7; ++ht) v = fmaxf(v, fabsf(acc[ct][ht][r]));
        im[ct][r] = v;
      }
#pragma unroll
    for (int o = 1; o < 16; o <<= 1)
#pragma unroll
      for (int ct = 0; ct < 2; ++ct)
#pragma unroll
        for (int r = 0; r < 4; ++r)
          im[ct][r] = fmaxf(im[ct][r], __shfl_xor(im[ct][r], o));
    if ((l & 15) == 0) {
#pragma unroll
      for (int ct = 0; ct < 2; ++ct)
#pragma unroll
        for (int r = 0; r < 4; ++r)
          sm.comax[(w << 5) + (ct << 4) + (g << 2) + r] = im[ct][r];
    }
    __syncthreads();
    float v = 0.f;
    if (t < 128) v = sm.comax[t] * (sf1 * wsf[t]);  // monotone: matches max over f32 y
    for (int o = 32; o > 0; o >>= 1) v = fmaxf(v, __shfl_xor(v, o));
    if ((t & 63) == 0) red2[t >> 6] = v;
    __syncthreads();
    if (t == 0)
      blockmax[blk] = fmaxf(fmaxf(red2[0], red2[1]), fmaxf(red2[2], red2[3]));
  } else {
    const float sf2 = sf2p[0];
    float fac[2][4];
#pragma unroll
    for (int ct = 0; ct < 2; ++ct)
#pragma unroll
      for (int r = 0; r < 4; ++r)
        fac[ct][r] = sf1 * wsf[(w << 5) + (ct << 4) + (g << 2) + r];
#pragma unroll
    for (int ct = 0; ct < 2; ++ct)
#pragma unroll
      for (int ht = 0; ht < 7; ++ht)
#pragma unroll
        for (int r = 0; r < 4; ++r) {
          const float y = acc[ct][ht][r] * fac[ct][r];
          const float q = fminf(fmaxf(rintf(y / sf2), -128.f), 127.f);
          sm.q2[(w << 5) + (ct << 4) + (g << 2) + r][ht * 16 + (l & 15)] = q;
        }
    __syncthreads();
    const long obase = (long)n * 100352 + tt * 28;
    for (int i = t; i < 3584; i += 256) {
      const unsigned co = (unsigned)i / 28u;
      const unsigned wo = (unsigned)i - co * 28u;
      const float a = sm.q2[co][2 * wo];
      const float b = sm.q2[co][2 * wo + 1];
      const float c = sm.q2[co][56 + 2 * wo];
      const float d = sm.q2[co][56 + 2 * wo + 1];
      const float avg = (a + b + c + d) * 0.25f;  // exact: small ints
      out[obase + (long)co * 784 + wo] = rintf(avg) * sf2;
    }
  }
}

__global__ __launch_bounds__(256) void k2b_sf2(
    const float* __restrict__ blockmax, float* __restrict__ sf2slot,
    float* __restrict__ outsf2) {
  const int t = threadIdx.x;
  __shared__ float red[4];
  float m = 0.f;
  for (int i = t; i < 1792; i += 256) m = fmaxf(m, blockmax[i]);
  for (int o = 32; o > 0; o >>= 1) m = fmaxf(m, __shfl_xor(m, o));
  if ((t & 63) == 0) red[t >> 6] = m;
  __syncthreads();
  if (t == 0) {
    const float sf2 = fmaxf(fmaxf(red[0], red[1]), fmaxf(red[2], red[3])) / QMAXF;
    sf2slot[0] = sf2;
    outsf2[0] = sf2;
  }
}

extern "C" void kernel_launch(void* const* d_in, const int* in_sizes, int n_in,
                              void* d_out, int out_size, void* d_ws, size_t ws_size,
                              hipStream_t stream) {
  const float* x     = (const float*)d_in[0];
  const float* actsf = (const float*)d_in[1];
  const float* bnw   = (const float*)d_in[2];
  const float* bnb   = (const float*)d_in[3];
  const float* bnm   = (const float*)d_in[4];
  const float* bnv   = (const float*)d_in[5];
  const float* cw    = (const float*)d_in[6];
  float* out = (float*)d_out;
  char* ws = (char*)d_ws;

  unsigned int* gmax1 = (unsigned int*)ws;            // 4 B
  float* sf2slot      = (float*)(ws + 4);             // 4 B
  float* scq          = (float*)(ws + 64);            // 256 f32
  float* shq          = (float*)(ws + 64 + 1024);     // 256 f32
  float* wsf          = (float*)(ws + 64 + 2048);     // 128 f32
  unsigned short* wq  = (unsigned short*)(ws + 4096); // 128*256 f16 = 64 KB
  float* blockmax     = (float*)(ws + 4096 + 65536);  // 1792 f32

  hipLaunchKernelGGL(k0_prep, dim3(1), dim3(256), 0, stream,
                     actsf, bnw, bnb, bnm, bnv, cw, wsf, scq, shq, wq, gmax1);
  hipLaunchKernelGGL(k1_maxz, dim3(2048), dim3(256), 0, stream, x, scq, shq, gmax1);
  hipLaunchKernelGGL(HIP_KERNEL_NAME(k2_gemm<false>), dim3(1792), dim3(256), 0, stream,
                     x, scq, shq, wq, wsf, gmax1, sf2slot, blockmax, out);
  hipLaunchKernelGGL(k2b_sf2, dim3(1), dim3(256), 0, stream,
                     blockmax, sf2slot, out + (out_size - 1));
  hipLaunchKernelGGL(HIP_KERNEL_NAME(k2_gemm<true>), dim3(1792), dim3(256), 0, stream,
                     x, scq, shq, wq, wsf, gmax1, sf2slot, blockmax, out);
}

// Round 2
// 193.752 us; speedup vs baseline: 1.6704x; 1.6704x over previous
//
#include <hip/hip_runtime.h>

#define QMAXF 127.0f

typedef _Float16 f16x4 __attribute__((ext_vector_type(4)));
typedef float f32x4 __attribute__((ext_vector_type(4)));
typedef int i32x4 __attribute__((ext_vector_type(4)));

// ============================ k0: prep (parallel) ============================
__global__ __launch_bounds__(256) void k0_prep(
    const float* __restrict__ actsf, const float* __restrict__ bnw,
    const float* __restrict__ bnb, const float* __restrict__ bnm,
    const float* __restrict__ bnv, const float* __restrict__ cw,
    float* __restrict__ wsf, float* __restrict__ scq, float* __restrict__ shq,
    unsigned short* __restrict__ wq16, signed char* __restrict__ wq8,
    unsigned int* __restrict__ gmax) {
  const int t = threadIdx.x;
  __shared__ float red[4];
  // ---- BN fold: thread t = channel ----
  float scale, shift;
  {
#pragma clang fp contract(off)
    float inv = 1.0f / sqrtf(bnv[t] + 1e-5f);
    scale = bnw[t] * inv;
    float tmp = bnm[t] * scale;
    shift = bnb[t] - tmp;
  }
  float a = fabsf(scale);
  for (int o = 32; o > 0; o >>= 1) a = fmaxf(a, __shfl_xor(a, o));
  if ((t & 63) == 0) red[t >> 6] = a;
  __syncthreads();
  const float amax = fmaxf(fmaxf(red[0], red[1]), fmaxf(red[2], red[3]));
  const float bn_sf = amax / QMAXF;
  scq[t] = fminf(fmaxf(rintf(scale / bn_sf), -128.f), 127.f) * bn_sf;
  const float bias_sf = bn_sf * actsf[0];
  shq[t] = rintf(shift / bias_sf) * bias_sf;
  if (t == 0) *gmax = 0u;
  // ---- weight quant: 2 threads per output row ----
  const int r = t >> 1, half = t & 1;
  const float4* wrow = (const float4*)(cw + r * 256 + half * 128);
  float mx = 0.f;
#pragma unroll
  for (int j = 0; j < 32; ++j) {
    const float4 v = wrow[j];
    mx = fmaxf(mx, fmaxf(fmaxf(fabsf(v.x), fabsf(v.y)), fmaxf(fabsf(v.z), fabsf(v.w))));
  }
  mx = fmaxf(mx, __shfl_xor(mx, 1));
  const float wsf_v = mx / QMAXF;
  if (half == 0) wsf[r] = wsf_v;
  unsigned* w16w = (unsigned*)wq16;
  int* w8w = (int*)wq8;
#pragma unroll
  for (int j = 0; j < 32; ++j) {
    const float4 v = wrow[j];
    const float q0 = fminf(fmaxf(rintf(v.x / wsf_v), -128.f), 127.f);
    const float q1 = fminf(fmaxf(rintf(v.y / wsf_v), -128.f), 127.f);
    const float q2 = fminf(fmaxf(rintf(v.z / wsf_v), -128.f), 127.f);
    const float q3 = fminf(fmaxf(rintf(v.w / wsf_v), -128.f), 127.f);
    w8w[r * 64 + half * 32 + j] =
        ((int)q0 & 255) | (((int)q1 & 255) << 8) | (((int)q2 & 255) << 16) | (((int)q3 & 255) << 24);
    const unsigned h0 = __builtin_bit_cast(unsigned short, (_Float16)q0);
    const unsigned h1 = __builtin_bit_cast(unsigned short, (_Float16)q1);
    const unsigned h2 = __builtin_bit_cast(unsigned short, (_Float16)q2);
    const unsigned h3 = __builtin_bit_cast(unsigned short, (_Float16)q3);
    w16w[r * 128 + half * 64 + 2 * j]     = h0 | (h1 << 16);
    w16w[r * 128 + half * 64 + 2 * j + 1] = h2 | (h3 << 16);
  }
}

// ============================ k1: global max of relu(bn(x)) ============================
__global__ __launch_bounds__(256) void k1_max(
    const float* __restrict__ x, const float* __restrict__ scq,
    const float* __restrict__ shq, unsigned int* __restrict__ gmax) {
  const int t = threadIdx.x;
  const int b = blockIdx.x;
  const int n = b >> 5, cg = b & 31;
  __shared__ float red[4];
  const float4* __restrict__ x4 = (const float4*)x + (long)(n * 256 + cg * 8) * 784;
  float m = 0.f;  // relu => max >= 0
  for (int r = 0; r < 8; ++r) {
    const float s = scq[cg * 8 + r], sh = shq[cg * 8 + r];
    const float4* row = x4 + r * 784;
    for (int j = t; j < 784; j += 256) {
      const float4 v = row[j];
      float z0, z1, z2, z3;
      {
#pragma clang fp contract(off)
        z0 = v.x * s + sh; z1 = v.y * s + sh; z2 = v.z * s + sh; z3 = v.w * s + sh;
      }
      m = fmaxf(m, fmaxf(fmaxf(z0, z1), fmaxf(z2, z3)));
    }
  }
  for (int o = 32; o > 0; o >>= 1) m = fmaxf(m, __shfl_xor(m, o));
  if ((t & 63) == 0) red[t >> 6] = m;
  __syncthreads();
  if (t == 0) {
    const float mm = fmaxf(fmaxf(red[0], red[1]), fmaxf(red[2], red[3]));
    atomicMax(gmax, __float_as_uint(mm));
  }
}

// ============================ k1c: quantize + transpose to NHWC int8 ============================
__global__ __launch_bounds__(256) void k1c_quant(
    const float* __restrict__ x, const float* __restrict__ scq,
    const float* __restrict__ shq, const unsigned int* __restrict__ gmax,
    signed char* __restrict__ xqT) {
  __shared__ int sw[112 * 64];  // [hw][ciword'] with XOR-swizzled word column
  const int t = threadIdx.x;
  const int blk = blockIdx.x;
  const int n = blk / 28, tt = blk - n * 28;
  const float sf1 = __uint_as_float(*gmax) / QMAXF;
  const float* __restrict__ xb = x + (long)n * 802816 + tt * 112;
  for (int it = 0; it < 28; ++it) {
    const int task = it * 256 + t;                 // 0..7167
    const unsigned ciq = (unsigned)task / 112u;    // 0..63
    const int hw = task - (int)ciq * 112;          // 0..111
    const int ci0 = (int)ciq * 4;
    int word = 0;
#pragma unroll
    for (int j = 0; j < 4; ++j) {
      const float v = xb[(ci0 + j) * 3136 + hw];
      const float s = scq[ci0 + j], sh = shq[ci0 + j];
      float z;
      {
#pragma clang fp contract(off)
        z = v * s + sh;
      }
      z = fmaxf(z, 0.f);
      const float q = fminf(fmaxf(rintf(z / sf1), -128.f), 127.f);
      word |= ((int)q & 255) << (8 * j);
    }
    sw[hw * 64 + ((int)ciq ^ (hw & 31))] = word;
  }
  __syncthreads();
  signed char* __restrict__ dst = xqT + ((long)(n * 3136 + tt * 112)) * 256;
  for (int it = 0; it < 7; ++it) {
    const int idx = it * 256 + t;
    const int hw = idx >> 4, c = idx & 15;
    int o4[4];
#pragma unroll
    for (int i = 0; i < 4; ++i) o4[i] = sw[hw * 64 + ((4 * c + i) ^ (hw & 31))];
    *(i32x4*)(dst + hw * 256 + c * 16) = *(i32x4*)o4;
  }
}

// ============================ k3: int8 MFMA GEMM (no LDS main loop) ============================
template <bool FINAL>
__global__ __launch_bounds__(256) void k3_gemm(
    const signed char* __restrict__ xqT, const signed char* __restrict__ wq8,
    const float* __restrict__ wsf, const unsigned int* __restrict__ gmax,
    const float* __restrict__ sf2p, float* __restrict__ blockmax,
    float* __restrict__ out) {
  __shared__ char smraw[FINAL ? (128 * 116 * 2) : 512];
  __shared__ float red2[4];
  const int t = threadIdx.x, w = t >> 6, l = t & 63;
  const int m = l & 15, g = l >> 4;
  const int blk = blockIdx.x;
  const int n = blk / 28, tt = blk - n * 28;
  const float sf1 = __uint_as_float(*gmax) / QMAXF;
  const signed char* __restrict__ xb = xqT + ((long)(n * 3136 + tt * 112)) * 256;

  i32x4 wf[2][4];
#pragma unroll
  for (int ct = 0; ct < 2; ++ct)
#pragma unroll
    for (int ks = 0; ks < 4; ++ks)
      wf[ct][ks] = *(const i32x4*)(wq8 + (w * 32 + ct * 16 + m) * 256 + ks * 64 + g * 16);

  i32x4 acc[2][7];
#pragma unroll
  for (int ct = 0; ct < 2; ++ct)
#pragma unroll
    for (int ht = 0; ht < 7; ++ht) acc[ct][ht] = (i32x4){0, 0, 0, 0};

#pragma unroll
  for (int ks = 0; ks < 4; ++ks) {
    i32x4 xf[7];
#pragma unroll
    for (int ht = 0; ht < 7; ++ht)
      xf[ht] = *(const i32x4*)(xb + (ht * 16 + m) * 256 + ks * 64 + g * 16);
#pragma unroll
    for (int ct = 0; ct < 2; ++ct)
#pragma unroll
      for (int ht = 0; ht < 7; ++ht)
        acc[ct][ht] = __builtin_amdgcn_mfma_i32_16x16x64_i8(wf[ct][ks], xf[ht], acc[ct][ht], 0, 0, 0);
  }

  if (!FINAL) {
    float* comax = (float*)smraw;
    int im[2][4];
#pragma unroll
    for (int ct = 0; ct < 2; ++ct)
#pragma unroll
      for (int r = 0; r < 4; ++r) {
        int v = 0;
#pragma unroll
        for (int ht = 0; ht < 7; ++ht) {
          int a = acc[ct][ht][r];
          a = a < 0 ? -a : a;
          v = a > v ? a : v;
        }
        im[ct][r] = v;
      }
#pragma unroll
    for (int o = 1; o < 16; o <<= 1)
#pragma unroll
      for (int ct = 0; ct < 2; ++ct)
#pragma unroll
        for (int r = 0; r < 4; ++r) {
          const int other = __shfl_xor(im[ct][r], o);
          im[ct][r] = other > im[ct][r] ? other : im[ct][r];
        }
    if (m == 0) {
#pragma unroll
      for (int ct = 0; ct < 2; ++ct)
#pragma unroll
        for (int r = 0; r < 4; ++r)
          comax[w * 32 + ct * 16 + g * 4 + r] = (float)im[ct][r];
    }
    __syncthreads();
    float v = 0.f;
    if (t < 128) v = comax[t] * (sf1 * wsf[t]);
    for (int o = 32; o > 0; o >>= 1) v = fmaxf(v, __shfl_xor(v, o));
    if ((t & 63) == 0) red2[t >> 6] = v;
    __syncthreads();
    if (t == 0)
      blockmax[blk] = fmaxf(fmaxf(red2[0], red2[1]), fmaxf(red2[2], red2[3]));
  } else {
    _Float16* q2 = (_Float16*)smraw;  // [128][116]
    const float sf2 = sf2p[0];
    float fac[2][4];
#pragma unroll
    for (int ct = 0; ct < 2; ++ct)
#pragma unroll
      for (int r = 0; r < 4; ++r)
        fac[ct][r] = sf1 * wsf[w * 32 + ct * 16 + g * 4 + r];
#pragma unroll
    for (int ct = 0; ct < 2; ++ct)
#pragma unroll
      for (int ht = 0; ht < 7; ++ht)
#pragma unroll
        for (int r = 0; r < 4; ++r) {
          const float y = (float)acc[ct][ht][r] * fac[ct][r];
          const float q = fminf(fmaxf(rintf(y / sf2), -128.f), 127.f);
          q2[(w * 32 + ct * 16 + g * 4 + r) * 116 + ht * 16 + m] = (_Float16)q;
        }
    __syncthreads();
    const long obase = (long)n * 100352 + tt * 28;
    for (int i = t; i < 3584; i += 256) {
      const unsigned co = (unsigned)i / 28u;
      const unsigned wo = (unsigned)i - co * 28u;
      const _Float16* row = q2 + co * 116;
      const float a = (float)row[2 * wo] + (float)row[2 * wo + 1] +
                      (float)row[56 + 2 * wo] + (float)row[56 + 2 * wo + 1];
      out[obase + (long)co * 784 + wo] = rintf(a * 0.25f) * sf2;
    }
  }
}

// ============================ k2b: sf2 reduce ============================
__global__ __launch_bounds__(256) void k2b_sf2(
    const float* __restrict__ blockmax, float* __restrict__ sf2slot,
    float* __restrict__ outsf2) {
  const int t = threadIdx.x;
  __shared__ float red[4];
  float m = 0.f;
  for (int i = t; i < 1792; i += 256) m = fmaxf(m, blockmax[i]);
  for (int o = 32; o > 0; o >>= 1) m = fmaxf(m, __shfl_xor(m, o));
  if ((t & 63) == 0) red[t >> 6] = m;
  __syncthreads();
  if (t == 0) {
    const float sf2 = fmaxf(fmaxf(red[0], red[1]), fmaxf(red[2], red[3])) / QMAXF;
    sf2slot[0] = sf2;
    outsf2[0] = sf2;
  }
}

// ============================ fallback: round-1 f16 GEMM (ws too small) ============================
union K2Smem {
  float xq[112][132];
  float q2[128][113];
  float comax[128];
};

template <bool FINAL>
__global__ __launch_bounds__(256, 2) void k2_gemm(
    const float* __restrict__ x, const float* __restrict__ scq,
    const float* __restrict__ shq, const unsigned short* __restrict__ wqu,
    const float* __restrict__ wsf, const unsigned int* __restrict__ gmax1,
    const float* __restrict__ sf2p, float* __restrict__ blockmax,
    float* __restrict__ out) {
  __shared__ K2Smem sm;
  __shared__ float red2[4];
  const int t = threadIdx.x;
  const int w = t >> 6;
  const int l = t & 63;
  const int blk = blockIdx.x;
  const int n = blk / 28;
  const int tt = blk - n * 28;
  const long xbase = (long)n * 802816 + tt * 112;
  const float sf1 = __uint_as_float(*gmax1) / QMAXF;
  const _Float16* __restrict__ wq16 = (const _Float16*)wqu;
  f32x4 acc[2][7];
#pragma unroll
  for (int ct = 0; ct < 2; ++ct)
#pragma unroll
    for (int ht = 0; ht < 7; ++ht) acc[ct][ht] = (f32x4){0.f, 0.f, 0.f, 0.f};

  for (int phase = 0; phase < 2; ++phase) {
    for (int it = 0; it < 14; ++it) {
      const unsigned f = (unsigned)t + (unsigned)it * 256u;
      const unsigned ci_l = f / 28u;
      const unsigned hwp = (f - ci_l * 28u) * 4u;
      const int ci = phase * 128 + (int)ci_l;
      const float4 v = *(const float4*)(x + xbase + (long)ci * 3136 + hwp);
      const float s = scq[ci], sh = shq[ci];
      float z0, z1, z2, z3;
      {
#pragma clang fp contract(off)
        z0 = v.x * s + sh; z1 = v.y * s + sh; z2 = v.z * s + sh; z3 = v.w * s + sh;
      }
      z0 = fmaxf(z0, 0.f); z1 = fmaxf(z1, 0.f); z2 = fmaxf(z2, 0.f); z3 = fmaxf(z3, 0.f);
      sm.xq[hwp + 0][ci_l] = fminf(fmaxf(rintf(z0 / sf1), -128.f), 127.f);
      sm.xq[hwp + 1][ci_l] = fminf(fmaxf(rintf(z1 / sf1), -128.f), 127.f);
      sm.xq[hwp + 2][ci_l] = fminf(fmaxf(rintf(z2 / sf1), -128.f), 127.f);
      sm.xq[hwp + 3][ci_l] = fminf(fmaxf(rintf(z3 / sf1), -128.f), 127.f);
    }
    __syncthreads();
    const int kw = ((l >> 4) << 2);
#pragma unroll
    for (int ks = 0; ks < 8; ++ks) {
      const int kb = ks * 16 + kw;
      f16x4 xf[7];
#pragma unroll
      for (int ht = 0; ht < 7; ++ht) {
        const float4 xv = *(const float4*)&sm.xq[ht * 16 + (l & 15)][kb];
        f16x4 h;
        h[0] = (_Float16)xv.x; h[1] = (_Float16)xv.y;
        h[2] = (_Float16)xv.z; h[3] = (_Float16)xv.w;
        xf[ht] = h;
      }
#pragma unroll
      for (int ct = 0; ct < 2; ++ct) {
        const int co = (w << 5) + (ct << 4) + (l & 15);
        const f16x4 wf = *(const f16x4*)(wq16 + co * 256 + phase * 128 + kb);
#pragma unroll
        for (int ht = 0; ht < 7; ++ht)
          acc[ct][ht] = __builtin_amdgcn_mfma_f32_16x16x16f16(wf, xf[ht], acc[ct][ht], 0, 0, 0);
      }
    }
    __syncthreads();
  }

  const int g = (l >> 4);
  if (!FINAL) {
    float im[2][4];
#pragma unroll
    for (int ct = 0; ct < 2; ++ct)
#pragma unroll
      for (int r = 0; r < 4; ++r) {
        float v = 0.f;
#pragma unroll
        for (int ht = 0; ht < 7; ++ht) v = fmaxf(v, fabsf(acc[ct][ht][r]));
        im[ct][r] = v;
      }
#pragma unroll
    for (int o = 1; o < 16; o <<= 1)
#pragma unroll
      for (int ct = 0; ct < 2; ++ct)
#pragma unroll
        for (int r = 0; r < 4; ++r)
          im[ct][r] = fmaxf(im[ct][r], __shfl_xor(im[ct][r], o));
    if ((l & 15) == 0) {
#pragma unroll
      for (int ct = 0; ct < 2; ++ct)
#pragma unroll
        for (int r = 0; r < 4; ++r)
          sm.comax[(w << 5) + (ct << 4) + (g << 2) + r] = im[ct][r];
    }
    __syncthreads();
    float v = 0.f;
    if (t < 128) v = sm.comax[t] * (sf1 * wsf[t]);
    for (int o = 32; o > 0; o >>= 1) v = fmaxf(v, __shfl_xor(v, o));
    if ((t & 63) == 0) red2[t >> 6] = v;
    __syncthreads();
    if (t == 0)
      blockmax[blk] = fmaxf(fmaxf(red2[0], red2[1]), fmaxf(red2[2], red2[3]));
  } else {
    const float sf2 = sf2p[0];
    float fac[2][4];
#pragma unroll
    for (int ct = 0; ct < 2; ++ct)
#pragma unroll
      for (int r = 0; r < 4; ++r)
        fac[ct][r] = sf1 * wsf[(w << 5) + (ct << 4) + (g << 2) + r];
#pragma unroll
    for (int ct = 0; ct < 2; ++ct)
#pragma unroll
      for (int ht = 0; ht < 7; ++ht)
#pragma unroll
        for (int r = 0; r < 4; ++r) {
          const float y = acc[ct][ht][r] * fac[ct][r];
          const float q = fminf(fmaxf(rintf(y / sf2), -128.f), 127.f);
          sm.q2[(w << 5) + (ct << 4) + (g << 2) + r][ht * 16 + (l & 15)] = q;
        }
    __syncthreads();
    const long obase = (long)n * 100352 + tt * 28;
    for (int i = t; i < 3584; i += 256) {
      const unsigned co = (unsigned)i / 28u;
      const unsigned wo = (unsigned)i - co * 28u;
      const float a = sm.q2[co][2 * wo];
      const float b = sm.q2[co][2 * wo + 1];
      const float c = sm.q2[co][56 + 2 * wo];
      const float d = sm.q2[co][56 + 2 * wo + 1];
      const float avg = (a + b + c + d) * 0.25f;
      out[obase + (long)co * 784 + wo] = rintf(avg) * sf2;
    }
  }
}

extern "C" void kernel_launch(void* const* d_in, const int* in_sizes, int n_in,
                              void* d_out, int out_size, void* d_ws, size_t ws_size,
                              hipStream_t stream) {
  const float* x     = (const float*)d_in[0];
  const float* actsf = (const float*)d_in[1];
  const float* bnw   = (const float*)d_in[2];
  const float* bnb   = (const float*)d_in[3];
  const float* bnm   = (const float*)d_in[4];
  const float* bnv   = (const float*)d_in[5];
  const float* cw    = (const float*)d_in[6];
  float* out = (float*)d_out;
  char* ws = (char*)d_ws;

  unsigned int* gmax  = (unsigned int*)ws;                 // 4 B
  float* sf2slot      = (float*)(ws + 8);                  // 4 B
  float* scq          = (float*)(ws + 1024);               // 256 f32
  float* shq          = (float*)(ws + 2048);               // 256 f32
  float* wsf          = (float*)(ws + 3072);               // 128 f32
  signed char* wq8    = (signed char*)(ws + 4096);         // 32 KB
  unsigned short* wq16= (unsigned short*)(ws + 36864);     // 64 KB
  float* blockmax     = (float*)(ws + 102400);             // 1792 f32
  signed char* xqT    = (signed char*)(ws + 131072);       // 51.4 MB (NHWC int8)
  const size_t NEED = 131072ull + 64ull * 3136ull * 256ull;

  hipLaunchKernelGGL(k0_prep, dim3(1), dim3(256), 0, stream,
                     actsf, bnw, bnb, bnm, bnv, cw, wsf, scq, shq, wq16, wq8, gmax);
  hipLaunchKernelGGL(k1_max, dim3(2048), dim3(256), 0, stream, x, scq, shq, gmax);
  if (ws_size >= NEED) {
    hipLaunchKernelGGL(k1c_quant, dim3(1792), dim3(256), 0, stream, x, scq, shq, gmax, xqT);
    hipLaunchKernelGGL(HIP_KERNEL_NAME(k3_gemm<false>), dim3(1792), dim3(256), 0, stream,
                       xqT, wq8, wsf, gmax, sf2slot, blockmax, out);
    hipLaunchKernelGGL(k2b_sf2, dim3(1), dim3(256), 0, stream,
                       blockmax, sf2slot, out + (out_size - 1));
    hipLaunchKernelGGL(HIP_KERNEL_NAME(k3_gemm<true>), dim3(1792), dim3(256), 0, stream,
                       xqT, wq8, wsf, gmax, sf2slot, blockmax, out);
  } else {
    hipLaunchKernelGGL(HIP_KERNEL_NAME(k2_gemm<false>), dim3(1792), dim3(256), 0, stream,
                       x, scq, shq, wq16, wsf, gmax, sf2slot, blockmax, out);
    hipLaunchKernelGGL(k2b_sf2, dim3(1), dim3(256), 0, stream,
                       blockmax, sf2slot, out + (out_size - 1));
    hipLaunchKernelGGL(HIP_KERNEL_NAME(k2_gemm<true>), dim3(1792), dim3(256), 0, stream,
                       x, scq, shq, wq16, wsf, gmax, sf2slot, blockmax, out);
  }
}

// Round 3
// 171.927 us; speedup vs baseline: 1.8824x; 1.1269x over previous
//
#include <hip/hip_runtime.h>

#define QMAXF 127.0f

typedef _Float16 f16x4 __attribute__((ext_vector_type(4)));
typedef float f32x4 __attribute__((ext_vector_type(4)));
typedef int i32x4 __attribute__((ext_vector_type(4)));

// ============================ k0: prep (parallel) ============================
__global__ __launch_bounds__(256) void k0_prep(
    const float* __restrict__ actsf, const float* __restrict__ bnw,
    const float* __restrict__ bnb, const float* __restrict__ bnm,
    const float* __restrict__ bnv, const float* __restrict__ cw,
    float* __restrict__ wsf, float* __restrict__ scq, float* __restrict__ shq,
    unsigned short* __restrict__ wq16, signed char* __restrict__ wq8,
    unsigned int* __restrict__ gmax) {
  const int t = threadIdx.x;
  __shared__ float red[4];
  // ---- BN fold: thread t = channel ----
  float scale, shift;
  {
#pragma clang fp contract(off)
    float inv = 1.0f / sqrtf(bnv[t] + 1e-5f);
    scale = bnw[t] * inv;
    float tmp = bnm[t] * scale;
    shift = bnb[t] - tmp;
  }
  float a = fabsf(scale);
  for (int o = 32; o > 0; o >>= 1) a = fmaxf(a, __shfl_xor(a, o));
  if ((t & 63) == 0) red[t >> 6] = a;
  __syncthreads();
  const float amax = fmaxf(fmaxf(red[0], red[1]), fmaxf(red[2], red[3]));
  const float bn_sf = amax / QMAXF;
  scq[t] = fminf(fmaxf(rintf(scale / bn_sf), -128.f), 127.f) * bn_sf;
  const float bias_sf = bn_sf * actsf[0];
  shq[t] = rintf(shift / bias_sf) * bias_sf;
  if (t == 0) *gmax = 0u;
  // ---- weight quant: 2 threads per output row ----
  const int r = t >> 1, half = t & 1;
  const float4* wrow = (const float4*)(cw + r * 256 + half * 128);
  float mx = 0.f;
#pragma unroll
  for (int j = 0; j < 32; ++j) {
    const float4 v = wrow[j];
    mx = fmaxf(mx, fmaxf(fmaxf(fabsf(v.x), fabsf(v.y)), fmaxf(fabsf(v.z), fabsf(v.w))));
  }
  mx = fmaxf(mx, __shfl_xor(mx, 1));
  const float wsf_v = mx / QMAXF;
  if (half == 0) wsf[r] = wsf_v;
  unsigned* w16w = (unsigned*)wq16;
  int* w8w = (int*)wq8;
#pragma unroll
  for (int j = 0; j < 32; ++j) {
    const float4 v = wrow[j];
    const float q0 = fminf(fmaxf(rintf(v.x / wsf_v), -128.f), 127.f);
    const float q1 = fminf(fmaxf(rintf(v.y / wsf_v), -128.f), 127.f);
    const float q2 = fminf(fmaxf(rintf(v.z / wsf_v), -128.f), 127.f);
    const float q3 = fminf(fmaxf(rintf(v.w / wsf_v), -128.f), 127.f);
    w8w[r * 64 + half * 32 + j] =
        ((int)q0 & 255) | (((int)q1 & 255) << 8) | (((int)q2 & 255) << 16) | (((int)q3 & 255) << 24);
    const unsigned h0 = __builtin_bit_cast(unsigned short, (_Float16)q0);
    const unsigned h1 = __builtin_bit_cast(unsigned short, (_Float16)q1);
    const unsigned h2 = __builtin_bit_cast(unsigned short, (_Float16)q2);
    const unsigned h3 = __builtin_bit_cast(unsigned short, (_Float16)q3);
    w16w[r * 128 + half * 64 + 2 * j]     = h0 | (h1 << 16);
    w16w[r * 128 + half * 64 + 2 * j + 1] = h2 | (h3 << 16);
  }
}

// ============================ k1: global max of relu(bn(x)) ============================
__global__ __launch_bounds__(256) void k1_max(
    const float* __restrict__ x, const float* __restrict__ scq,
    const float* __restrict__ shq, unsigned int* __restrict__ gmax) {
  const int t = threadIdx.x;
  const int b = blockIdx.x;
  const int n = b >> 5, cg = b & 31;
  __shared__ float red[4];
  const float4* __restrict__ x4 = (const float4*)x + (long)(n * 256 + cg * 8) * 784;
  float m = 0.f;  // relu => max >= 0
  for (int r = 0; r < 8; ++r) {
    const float s = scq[cg * 8 + r], sh = shq[cg * 8 + r];
    const float4* row = x4 + r * 784;
    for (int j = t; j < 784; j += 256) {
      const float4 v = row[j];
      float z0, z1, z2, z3;
      {
#pragma clang fp contract(off)
        z0 = v.x * s + sh; z1 = v.y * s + sh; z2 = v.z * s + sh; z3 = v.w * s + sh;
      }
      m = fmaxf(m, fmaxf(fmaxf(z0, z1), fmaxf(z2, z3)));
    }
  }
  for (int o = 32; o > 0; o >>= 1) m = fmaxf(m, __shfl_xor(m, o));
  if ((t & 63) == 0) red[t >> 6] = m;
  __syncthreads();
  if (t == 0) {
    const float mm = fmaxf(fmaxf(red[0], red[1]), fmaxf(red[2], red[3]));
    atomicMax(gmax, __float_as_uint(mm));
  }
}

// ===== k2f: fused quantize + transpose-to-LDS + xqT write + int8 MFMA max pass =====
// Block (n,tt): 112 hw x 256 ci. LDS [hw][16 slots of 16B], slot XOR-swizzled by hw&7
// so every b128 LDS access (write, xqT readout, MFMA fragment read) is at the 8-cyc floor.
__global__ __launch_bounds__(256, 2) void k2f_quant_gemm(
    const float* __restrict__ x, const float* __restrict__ scq,
    const float* __restrict__ shq, const unsigned int* __restrict__ gmax,
    const signed char* __restrict__ wq8, const float* __restrict__ wsf,
    signed char* __restrict__ xqT, float* __restrict__ blockmax) {
  __shared__ int sw[112 * 64];  // 28 KB
  __shared__ float comax[128];
  __shared__ float red2[4];
  const int t = threadIdx.x, w = t >> 6, l = t & 63, m = l & 15, g = l >> 4;
  const int blk = blockIdx.x, n = blk / 28, tt = blk - n * 28;
  const float sf1 = __uint_as_float(*gmax) / QMAXF;
  const float* __restrict__ xb = x + (long)n * 802816 + tt * 112;

  // ---- quantize: 448 tasks, task = (hwq 0..27, slot 0..15) -> 4 hw x 16 ci ----
  for (int it = 0; it < 2; ++it) {
    const int task = it * 256 + t;
    if (task < 448) {
      const int slot = task & 15, hwq = task >> 4;
      const int hw0 = hwq * 4, ci0 = slot * 16;
      int wbuf[4][4] = {{0, 0, 0, 0}, {0, 0, 0, 0}, {0, 0, 0, 0}, {0, 0, 0, 0}};
#pragma unroll
      for (int j = 0; j < 16; ++j) {
        const float4 v = *(const float4*)(xb + (long)(ci0 + j) * 3136 + hw0);
        const float s = scq[ci0 + j], sh = shq[ci0 + j];
        float z0, z1, z2, z3;
        {
#pragma clang fp contract(off)
          z0 = v.x * s + sh; z1 = v.y * s + sh; z2 = v.z * s + sh; z3 = v.w * s + sh;
        }
        const float q0 = fminf(fmaxf(rintf(fmaxf(z0, 0.f) / sf1), -128.f), 127.f);
        const float q1 = fminf(fmaxf(rintf(fmaxf(z1, 0.f) / sf1), -128.f), 127.f);
        const float q2 = fminf(fmaxf(rintf(fmaxf(z2, 0.f) / sf1), -128.f), 127.f);
        const float q3 = fminf(fmaxf(rintf(fmaxf(z3, 0.f) / sf1), -128.f), 127.f);
        wbuf[0][j >> 2] |= ((int)q0 & 255) << ((j & 3) * 8);
        wbuf[1][j >> 2] |= ((int)q1 & 255) << ((j & 3) * 8);
        wbuf[2][j >> 2] |= ((int)q2 & 255) << ((j & 3) * 8);
        wbuf[3][j >> 2] |= ((int)q3 & 255) << ((j & 3) * 8);
      }
#pragma unroll
      for (int dh = 0; dh < 4; ++dh) {
        const int hw = hw0 + dh;
        *(i32x4*)&sw[hw * 64 + ((slot ^ (hw & 7)) << 2)] = *(const i32x4*)wbuf[dh];
      }
    }
  }
  __syncthreads();

  // ---- write xqT (coalesced 1KB/wave) ----
  signed char* __restrict__ dst = xqT + ((long)(n * 3136 + tt * 112)) * 256;
  for (int it = 0; it < 7; ++it) {
    const int idx = it * 256 + t;
    const int hw = idx >> 4, c = idx & 15;
    const i32x4 v = *(const i32x4*)&sw[hw * 64 + ((c ^ (hw & 7)) << 2)];
    *(i32x4*)(dst + hw * 256 + c * 16) = v;
  }

  // ---- int8 MFMA from LDS ----
  i32x4 wf[2][4];
#pragma unroll
  for (int ct = 0; ct < 2; ++ct)
#pragma unroll
    for (int ks = 0; ks < 4; ++ks)
      wf[ct][ks] = *(const i32x4*)(wq8 + (w * 32 + ct * 16 + m) * 256 + ks * 64 + g * 16);

  i32x4 acc[2][7];
#pragma unroll
  for (int ct = 0; ct < 2; ++ct)
#pragma unroll
    for (int ht = 0; ht < 7; ++ht) acc[ct][ht] = (i32x4){0, 0, 0, 0};

#pragma unroll
  for (int ks = 0; ks < 4; ++ks) {
    i32x4 xf[7];
#pragma unroll
    for (int ht = 0; ht < 7; ++ht) {
      const int row = ht * 16 + m;
      xf[ht] = *(const i32x4*)&sw[row * 64 + (((ks * 4 + g) ^ (row & 7)) << 2)];
    }
#pragma unroll
    for (int ct = 0; ct < 2; ++ct)
#pragma unroll
      for (int ht = 0; ht < 7; ++ht)
        acc[ct][ht] = __builtin_amdgcn_mfma_i32_16x16x64_i8(wf[ct][ks], xf[ht], acc[ct][ht], 0, 0, 0);
  }

  // ---- per-co |y_int| max -> blockmax ----
  int im[2][4];
#pragma unroll
  for (int ct = 0; ct < 2; ++ct)
#pragma unroll
    for (int r = 0; r < 4; ++r) {
      int v = 0;
#pragma unroll
      for (int ht = 0; ht < 7; ++ht) {
        int a = acc[ct][ht][r];
        a = a < 0 ? -a : a;
        v = a > v ? a : v;
      }
      im[ct][r] = v;
    }
#pragma unroll
  for (int o = 1; o < 16; o <<= 1)
#pragma unroll
    for (int ct = 0; ct < 2; ++ct)
#pragma unroll
      for (int r = 0; r < 4; ++r) {
        const int other = __shfl_xor(im[ct][r], o);
        im[ct][r] = other > im[ct][r] ? other : im[ct][r];
      }
  if (m == 0) {
#pragma unroll
    for (int ct = 0; ct < 2; ++ct)
#pragma unroll
      for (int r = 0; r < 4; ++r)
        comax[w * 32 + ct * 16 + g * 4 + r] = (float)im[ct][r];
  }
  __syncthreads();
  float v = 0.f;
  if (t < 128) v = comax[t] * (sf1 * wsf[t]);
  for (int o = 32; o > 0; o >>= 1) v = fmaxf(v, __shfl_xor(v, o));
  if ((t & 63) == 0) red2[t >> 6] = v;
  __syncthreads();
  if (t == 0)
    blockmax[blk] = fmaxf(fmaxf(red2[0], red2[1]), fmaxf(red2[2], red2[3]));
}

// ============================ k2b: sf2 reduce ============================
__global__ __launch_bounds__(256) void k2b_sf2(
    const float* __restrict__ blockmax, float* __restrict__ sf2slot,
    float* __restrict__ outsf2) {
  const int t = threadIdx.x;
  __shared__ float red[4];
  float m = 0.f;
  for (int i = t; i < 1792; i += 256) m = fmaxf(m, blockmax[i]);
  for (int o = 32; o > 0; o >>= 1) m = fmaxf(m, __shfl_xor(m, o));
  if ((t & 63) == 0) red[t >> 6] = m;
  __syncthreads();
  if (t == 0) {
    const float sf2 = fmaxf(fmaxf(red[0], red[1]), fmaxf(red[2], red[3])) / QMAXF;
    sf2slot[0] = sf2;
    outsf2[0] = sf2;
  }
}

// ============================ k3: final int8 GEMM + requant + pool ============================
__global__ __launch_bounds__(256) void k3_final(
    const signed char* __restrict__ xqT, const signed char* __restrict__ wq8,
    const float* __restrict__ wsf, const unsigned int* __restrict__ gmax,
    const float* __restrict__ sf2p, float* __restrict__ out) {
  __shared__ _Float16 q2[128 * 116];
  const int t = threadIdx.x, w = t >> 6, l = t & 63;
  const int m = l & 15, g = l >> 4;
  const int blk = blockIdx.x;
  const int n = blk / 28, tt = blk - n * 28;
  const float sf1 = __uint_as_float(*gmax) / QMAXF;
  const signed char* __restrict__ xb = xqT + ((long)(n * 3136 + tt * 112)) * 256;

  i32x4 wf[2][4];
#pragma unroll
  for (int ct = 0; ct < 2; ++ct)
#pragma unroll
    for (int ks = 0; ks < 4; ++ks)
      wf[ct][ks] = *(const i32x4*)(wq8 + (w * 32 + ct * 16 + m) * 256 + ks * 64 + g * 16);

  i32x4 acc[2][7];
#pragma unroll
  for (int ct = 0; ct < 2; ++ct)
#pragma unroll
    for (int ht = 0; ht < 7; ++ht) acc[ct][ht] = (i32x4){0, 0, 0, 0};

#pragma unroll
  for (int ks = 0; ks < 4; ++ks) {
    i32x4 xf[7];
#pragma unroll
    for (int ht = 0; ht < 7; ++ht)
      xf[ht] = *(const i32x4*)(xb + (ht * 16 + m) * 256 + ks * 64 + g * 16);
#pragma unroll
    for (int ct = 0; ct < 2; ++ct)
#pragma unroll
      for (int ht = 0; ht < 7; ++ht)
        acc[ct][ht] = __builtin_amdgcn_mfma_i32_16x16x64_i8(wf[ct][ks], xf[ht], acc[ct][ht], 0, 0, 0);
  }

  const float sf2 = sf2p[0];
  float fac[2][4];
#pragma unroll
  for (int ct = 0; ct < 2; ++ct)
#pragma unroll
    for (int r = 0; r < 4; ++r)
      fac[ct][r] = sf1 * wsf[w * 32 + ct * 16 + g * 4 + r];
#pragma unroll
  for (int ct = 0; ct < 2; ++ct)
#pragma unroll
    for (int ht = 0; ht < 7; ++ht)
#pragma unroll
      for (int r = 0; r < 4; ++r) {
        const float y = (float)acc[ct][ht][r] * fac[ct][r];
        const float q = fminf(fmaxf(rintf(y / sf2), -128.f), 127.f);
        q2[(w * 32 + ct * 16 + g * 4 + r) * 116 + ht * 16 + m] = (_Float16)q;
      }
  __syncthreads();
  const long obase = (long)n * 100352 + tt * 28;
  for (int i = t; i < 3584; i += 256) {
    const unsigned co = (unsigned)i / 28u;
    const unsigned wo = (unsigned)i - co * 28u;
    const _Float16* row = q2 + co * 116;
    const float a = (float)row[2 * wo] + (float)row[2 * wo + 1] +
                    (float)row[56 + 2 * wo] + (float)row[56 + 2 * wo + 1];
    out[obase + (long)co * 784 + wo] = rintf(a * 0.25f) * sf2;
  }
}

// ============================ fallback (ws too small): R1 f16 GEMM ============================
union K2Smem {
  float xq[112][132];
  float q2[128][113];
  float comax[128];
};

template <bool FINAL>
__global__ __launch_bounds__(256, 2) void k2_gemm(
    const float* __restrict__ x, const float* __restrict__ scq,
    const float* __restrict__ shq, const unsigned short* __restrict__ wqu,
    const float* __restrict__ wsf, const unsigned int* __restrict__ gmax1,
    const float* __restrict__ sf2p, float* __restrict__ blockmax,
    float* __restrict__ out) {
  __shared__ K2Smem sm;
  __shared__ float red2[4];
  const int t = threadIdx.x;
  const int w = t >> 6;
  const int l = t & 63;
  const int blk = blockIdx.x;
  const int n = blk / 28;
  const int tt = blk - n * 28;
  const long xbase = (long)n * 802816 + tt * 112;
  const float sf1 = __uint_as_float(*gmax1) / QMAXF;
  const _Float16* __restrict__ wq16 = (const _Float16*)wqu;
  f32x4 acc[2][7];
#pragma unroll
  for (int ct = 0; ct < 2; ++ct)
#pragma unroll
    for (int ht = 0; ht < 7; ++ht) acc[ct][ht] = (f32x4){0.f, 0.f, 0.f, 0.f};

  for (int phase = 0; phase < 2; ++phase) {
    for (int it = 0; it < 14; ++it) {
      const unsigned f = (unsigned)t + (unsigned)it * 256u;
      const unsigned ci_l = f / 28u;
      const unsigned hwp = (f - ci_l * 28u) * 4u;
      const int ci = phase * 128 + (int)ci_l;
      const float4 v = *(const float4*)(x + xbase + (long)ci * 3136 + hwp);
      const float s = scq[ci], sh = shq[ci];
      float z0, z1, z2, z3;
      {
#pragma clang fp contract(off)
        z0 = v.x * s + sh; z1 = v.y * s + sh; z2 = v.z * s + sh; z3 = v.w * s + sh;
      }
      z0 = fmaxf(z0, 0.f); z1 = fmaxf(z1, 0.f); z2 = fmaxf(z2, 0.f); z3 = fmaxf(z3, 0.f);
      sm.xq[hwp + 0][ci_l] = fminf(fmaxf(rintf(z0 / sf1), -128.f), 127.f);
      sm.xq[hwp + 1][ci_l] = fminf(fmaxf(rintf(z1 / sf1), -128.f), 127.f);
      sm.xq[hwp + 2][ci_l] = fminf(fmaxf(rintf(z2 / sf1), -128.f), 127.f);
      sm.xq[hwp + 3][ci_l] = fminf(fmaxf(rintf(z3 / sf1), -128.f), 127.f);
    }
    __syncthreads();
    const int kw = ((l >> 4) << 2);
#pragma unroll
    for (int ks = 0; ks < 8; ++ks) {
      const int kb = ks * 16 + kw;
      f16x4 xf[7];
#pragma unroll
      for (int ht = 0; ht < 7; ++ht) {
        const float4 xv = *(const float4*)&sm.xq[ht * 16 + (l & 15)][kb];
        f16x4 h;
        h[0] = (_Float16)xv.x; h[1] = (_Float16)xv.y;
        h[2] = (_Float16)xv.z; h[3] = (_Float16)xv.w;
        xf[ht] = h;
      }
#pragma unroll
      for (int ct = 0; ct < 2; ++ct) {
        const int co = (w << 5) + (ct << 4) + (l & 15);
        const f16x4 wfv = *(const f16x4*)(wq16 + co * 256 + phase * 128 + kb);
#pragma unroll
        for (int ht = 0; ht < 7; ++ht)
          acc[ct][ht] = __builtin_amdgcn_mfma_f32_16x16x16f16(wfv, xf[ht], acc[ct][ht], 0, 0, 0);
      }
    }
    __syncthreads();
  }

  const int g = (l >> 4);
  if (!FINAL) {
    float im[2][4];
#pragma unroll
    for (int ct = 0; ct < 2; ++ct)
#pragma unroll
      for (int r = 0; r < 4; ++r) {
        float v = 0.f;
#pragma unroll
        for (int ht = 0; ht < 7; ++ht) v = fmaxf(v, fabsf(acc[ct][ht][r]));
        im[ct][r] = v;
      }
#pragma unroll
    for (int o = 1; o < 16; o <<= 1)
#pragma unroll
      for (int ct = 0; ct < 2; ++ct)
#pragma unroll
        for (int r = 0; r < 4; ++r)
          im[ct][r] = fmaxf(im[ct][r], __shfl_xor(im[ct][r], o));
    if ((l & 15) == 0) {
#pragma unroll
      for (int ct = 0; ct < 2; ++ct)
#pragma unroll
        for (int r = 0; r < 4; ++r)
          sm.comax[(w << 5) + (ct << 4) + (g << 2) + r] = im[ct][r];
    }
    __syncthreads();
    float v = 0.f;
    if (t < 128) v = sm.comax[t] * (sf1 * wsf[t]);
    for (int o = 32; o > 0; o >>= 1) v = fmaxf(v, __shfl_xor(v, o));
    if ((t & 63) == 0) red2[t >> 6] = v;
    __syncthreads();
    if (t == 0)
      blockmax[blk] = fmaxf(fmaxf(red2[0], red2[1]), fmaxf(red2[2], red2[3]));
  } else {
    const float sf2 = sf2p[0];
    float fac[2][4];
#pragma unroll
    for (int ct = 0; ct < 2; ++ct)
#pragma unroll
      for (int r = 0; r < 4; ++r)
        fac[ct][r] = sf1 * wsf[(w << 5) + (ct << 4) + (g << 2) + r];
#pragma unroll
    for (int ct = 0; ct < 2; ++ct)
#pragma unroll
      for (int ht = 0; ht < 7; ++ht)
#pragma unroll
        for (int r = 0; r < 4; ++r) {
          const float y = acc[ct][ht][r] * fac[ct][r];
          const float q = fminf(fmaxf(rintf(y / sf2), -128.f), 127.f);
          sm.q2[(w << 5) + (ct << 4) + (g << 2) + r][ht * 16 + (l & 15)] = q;
        }
    __syncthreads();
    const long obase = (long)n * 100352 + tt * 28;
    for (int i = t; i < 3584; i += 256) {
      const unsigned co = (unsigned)i / 28u;
      const unsigned wo = (unsigned)i - co * 28u;
      const float a = sm.q2[co][2 * wo];
      const float b = sm.q2[co][2 * wo + 1];
      const float c = sm.q2[co][56 + 2 * wo];
      const float d = sm.q2[co][56 + 2 * wo + 1];
      const float avg = (a + b + c + d) * 0.25f;
      out[obase + (long)co * 784 + wo] = rintf(avg) * sf2;
    }
  }
}

extern "C" void kernel_launch(void* const* d_in, const int* in_sizes, int n_in,
                              void* d_out, int out_size, void* d_ws, size_t ws_size,
                              hipStream_t stream) {
  const float* x     = (const float*)d_in[0];
  const float* actsf = (const float*)d_in[1];
  const float* bnw   = (const float*)d_in[2];
  const float* bnb   = (const float*)d_in[3];
  const float* bnm   = (const float*)d_in[4];
  const float* bnv   = (const float*)d_in[5];
  const float* cw    = (const float*)d_in[6];
  float* out = (float*)d_out;
  char* ws = (char*)d_ws;

  unsigned int* gmax  = (unsigned int*)ws;                 // 4 B
  float* sf2slot      = (float*)(ws + 8);                  // 4 B
  float* scq          = (float*)(ws + 1024);               // 256 f32
  float* shq          = (float*)(ws + 2048);               // 256 f32
  float* wsf          = (float*)(ws + 3072);               // 128 f32
  signed char* wq8    = (signed char*)(ws + 4096);         // 32 KB
  unsigned short* wq16= (unsigned short*)(ws + 36864);     // 64 KB
  float* blockmax     = (float*)(ws + 102400);             // 1792 f32
  signed char* xqT    = (signed char*)(ws + 131072);       // 51.4 MB (NHWC int8)
  const size_t NEED = 131072ull + 64ull * 3136ull * 256ull;

  hipLaunchKernelGGL(k0_prep, dim3(1), dim3(256), 0, stream,
                     actsf, bnw, bnb, bnm, bnv, cw, wsf, scq, shq, wq16, wq8, gmax);
  hipLaunchKernelGGL(k1_max, dim3(2048), dim3(256), 0, stream, x, scq, shq, gmax);
  if (ws_size >= NEED) {
    hipLaunchKernelGGL(k2f_quant_gemm, dim3(1792), dim3(256), 0, stream,
                       x, scq, shq, gmax, wq8, wsf, xqT, blockmax);
    hipLaunchKernelGGL(k2b_sf2, dim3(1), dim3(256), 0, stream,
                       blockmax, sf2slot, out + (out_size - 1));
    hipLaunchKernelGGL(k3_final, dim3(1792), dim3(256), 0, stream,
                       xqT, wq8, wsf, gmax, sf2slot, out);
  } else {
    hipLaunchKernelGGL(HIP_KERNEL_NAME(k2_gemm<false>), dim3(1792), dim3(256), 0, stream,
                       x, scq, shq, wq16, wsf, gmax, sf2slot, blockmax, out);
    hipLaunchKernelGGL(k2b_sf2, dim3(1), dim3(256), 0, stream,
                       blockmax, sf2slot, out + (out_size - 1));
    hipLaunchKernelGGL(HIP_KERNEL_NAME(k2_gemm<true>), dim3(1792), dim3(256), 0, stream,
                       x, scq, shq, wq16, wsf, gmax, sf2slot, blockmax, out);
  }
}

// Round 4
// 168.635 us; speedup vs baseline: 1.9192x; 1.0195x over previous
//
#include <hip/hip_runtime.h>

#define QMAXF 127.0f

typedef float f32x4 __attribute__((ext_vector_type(4)));
typedef int i32x4 __attribute__((ext_vector_type(4)));

// ============================ k0: prep (parallel) ============================
__global__ __launch_bounds__(256) void k0_prep(
    const float* __restrict__ actsf, const float* __restrict__ bnw,
    const float* __restrict__ bnb, const float* __restrict__ bnm,
    const float* __restrict__ bnv, const float* __restrict__ cw,
    float* __restrict__ wsf, float* __restrict__ scq, float* __restrict__ shq,
    signed char* __restrict__ wq8, unsigned int* __restrict__ gmax) {
  const int t = threadIdx.x;
  __shared__ float red[4];
  // ---- BN fold: thread t = channel ----
  float scale, shift;
  {
#pragma clang fp contract(off)
    float inv = 1.0f / sqrtf(bnv[t] + 1e-5f);
    scale = bnw[t] * inv;
    float tmp = bnm[t] * scale;
    shift = bnb[t] - tmp;
  }
  float a = fabsf(scale);
  for (int o = 32; o > 0; o >>= 1) a = fmaxf(a, __shfl_xor(a, o));
  if ((t & 63) == 0) red[t >> 6] = a;
  __syncthreads();
  const float amax = fmaxf(fmaxf(red[0], red[1]), fmaxf(red[2], red[3]));
  const float bn_sf = amax / QMAXF;
  scq[t] = fminf(fmaxf(rintf(scale / bn_sf), -128.f), 127.f) * bn_sf;
  const float bias_sf = bn_sf * actsf[0];
  shq[t] = rintf(shift / bias_sf) * bias_sf;
  if (t == 0) *gmax = 0u;
  // ---- weight quant: 2 threads per output row ----
  const int r = t >> 1, half = t & 1;
  const float4* wrow = (const float4*)(cw + r * 256 + half * 128);
  float mx = 0.f;
#pragma unroll
  for (int j = 0; j < 32; ++j) {
    const float4 v = wrow[j];
    mx = fmaxf(mx, fmaxf(fmaxf(fabsf(v.x), fabsf(v.y)), fmaxf(fabsf(v.z), fabsf(v.w))));
  }
  mx = fmaxf(mx, __shfl_xor(mx, 1));
  const float wsf_v = mx / QMAXF;
  if (half == 0) wsf[r] = wsf_v;
  int* w8w = (int*)wq8;
#pragma unroll
  for (int j = 0; j < 32; ++j) {
    const float4 v = wrow[j];
    const float q0 = fminf(fmaxf(rintf(v.x / wsf_v), -128.f), 127.f);
    const float q1 = fminf(fmaxf(rintf(v.y / wsf_v), -128.f), 127.f);
    const float q2 = fminf(fmaxf(rintf(v.z / wsf_v), -128.f), 127.f);
    const float q3 = fminf(fmaxf(rintf(v.w / wsf_v), -128.f), 127.f);
    w8w[r * 64 + half * 32 + j] =
        ((int)q0 & 255) | (((int)q1 & 255) << 8) | (((int)q2 & 255) << 16) | (((int)q3 & 255) << 24);
  }
}

// ============================ k1: global max of relu(bn(x)) ============================
__global__ __launch_bounds__(256) void k1_max(
    const float* __restrict__ x, const float* __restrict__ scq,
    const float* __restrict__ shq, unsigned int* __restrict__ gmax) {
  const int t = threadIdx.x;
  const int b = blockIdx.x;
  const int n = b >> 5, cg = b & 31;
  __shared__ float red[4];
  const float4* __restrict__ x4 = (const float4*)x + (long)(n * 256 + cg * 8) * 784;
  float m = 0.f;  // relu => max >= 0
  for (int r = 0; r < 8; ++r) {
    const float s = scq[cg * 8 + r], sh = shq[cg * 8 + r];
    const float4* row = x4 + r * 784;
    for (int j = t; j < 784; j += 256) {
      const float4 v = row[j];
      float z0, z1, z2, z3;
      {
#pragma clang fp contract(off)
        z0 = v.x * s + sh; z1 = v.y * s + sh; z2 = v.z * s + sh; z3 = v.w * s + sh;
      }
      m = fmaxf(m, fmaxf(fmaxf(z0, z1), fmaxf(z2, z3)));
    }
  }
  for (int o = 32; o > 0; o >>= 1) m = fmaxf(m, __shfl_xor(m, o));
  if ((t & 63) == 0) red[t >> 6] = m;
  __syncthreads();
  if (t == 0) {
    const float mm = fmaxf(fmaxf(red[0], red[1]), fmaxf(red[2], red[3]));
    atomicMax(gmax, __float_as_uint(mm));
  }
}

// ===== k2f: fused quantize + transpose-to-LDS + xqT write + int8 MFMA max pass =====
// Tile: 64 hw x 256 ci. LDS [64 hw][16 slots of 16B], slot ^ (hw&7) swizzle.
// One quantize task per thread (16 ci x 4 hw). 4 blocks/CU target.
__global__ __launch_bounds__(256, 4) void k2f_quant_gemm(
    const float* __restrict__ x, const float* __restrict__ scq,
    const float* __restrict__ shq, const unsigned int* __restrict__ gmax,
    const signed char* __restrict__ wq8, const float* __restrict__ wsf,
    signed char* __restrict__ xqT, float* __restrict__ blockmax) {
  __shared__ int sw[64 * 64];  // 16 KB
  __shared__ float comax[128];
  __shared__ float red2[4];
  const int t = threadIdx.x, w = t >> 6, l = t & 63, m = l & 15, g = l >> 4;
  const int blk = blockIdx.x, n = blk / 49, tt = blk - n * 49;
  const float sf1 = __uint_as_float(*gmax) / QMAXF;
  const float* __restrict__ xb = x + (long)n * 802816 + tt * 64;

  // ---- quantize: one task/thread: slot = t&15 (16 ci), hwq = t>>4 (4 hw) ----
  {
    const int slot = t & 15, hwq = t >> 4;
    const int hw0 = hwq * 4, ci0 = slot * 16;
    int wbuf[4][4] = {{0, 0, 0, 0}, {0, 0, 0, 0}, {0, 0, 0, 0}, {0, 0, 0, 0}};
#pragma unroll
    for (int j = 0; j < 16; ++j) {
      const float4 v = *(const float4*)(xb + (long)(ci0 + j) * 3136 + hw0);
      const float s = scq[ci0 + j], sh = shq[ci0 + j];
      float z0, z1, z2, z3;
      {
#pragma clang fp contract(off)
        z0 = v.x * s + sh; z1 = v.y * s + sh; z2 = v.z * s + sh; z3 = v.w * s + sh;
      }
      const float q0 = fminf(fmaxf(rintf(fmaxf(z0, 0.f) / sf1), -128.f), 127.f);
      const float q1 = fminf(fmaxf(rintf(fmaxf(z1, 0.f) / sf1), -128.f), 127.f);
      const float q2 = fminf(fmaxf(rintf(fmaxf(z2, 0.f) / sf1), -128.f), 127.f);
      const float q3 = fminf(fmaxf(rintf(fmaxf(z3, 0.f) / sf1), -128.f), 127.f);
      wbuf[0][j >> 2] |= ((int)q0 & 255) << ((j & 3) * 8);
      wbuf[1][j >> 2] |= ((int)q1 & 255) << ((j & 3) * 8);
      wbuf[2][j >> 2] |= ((int)q2 & 255) << ((j & 3) * 8);
      wbuf[3][j >> 2] |= ((int)q3 & 255) << ((j & 3) * 8);
    }
#pragma unroll
    for (int dh = 0; dh < 4; ++dh) {
      const int hw = hw0 + dh;
      *(i32x4*)&sw[hw * 64 + ((slot ^ (hw & 7)) << 2)] = *(const i32x4*)wbuf[dh];
    }
  }
  __syncthreads();

  // ---- write xqT (fully coalesced: 1 KB per wave instr) ----
  signed char* __restrict__ dst = xqT + ((long)(n * 3136 + tt * 64)) * 256;
#pragma unroll
  for (int it = 0; it < 4; ++it) {
    const int idx = it * 256 + t;
    const int hw = idx >> 4, c = idx & 15;
    const i32x4 v = *(const i32x4*)&sw[hw * 64 + ((c ^ (hw & 7)) << 2)];
    *(i32x4*)(dst + hw * 256 + c * 16) = v;
  }

  // ---- int8 MFMA from LDS: 4 ht x 2 ct x 4 ks ----
  i32x4 acc[2][4];
#pragma unroll
  for (int ct = 0; ct < 2; ++ct)
#pragma unroll
    for (int ht = 0; ht < 4; ++ht) acc[ct][ht] = (i32x4){0, 0, 0, 0};

#pragma unroll
  for (int ct = 0; ct < 2; ++ct) {
#pragma unroll
    for (int ks = 0; ks < 4; ++ks) {
      const i32x4 wf = *(const i32x4*)(wq8 + (w * 32 + ct * 16 + m) * 256 + ks * 64 + g * 16);
#pragma unroll
      for (int ht = 0; ht < 4; ++ht) {
        const int row = ht * 16 + m;
        const i32x4 xf = *(const i32x4*)&sw[row * 64 + (((ks * 4 + g) ^ (row & 7)) << 2)];
        acc[ct][ht] = __builtin_amdgcn_mfma_i32_16x16x64_i8(wf, xf, acc[ct][ht], 0, 0, 0);
      }
    }
  }

  // ---- per-co |y_int| max -> blockmax ----
  int im[2][4];
#pragma unroll
  for (int ct = 0; ct < 2; ++ct)
#pragma unroll
    for (int r = 0; r < 4; ++r) {
      int v = 0;
#pragma unroll
      for (int ht = 0; ht < 4; ++ht) {
        int a = acc[ct][ht][r];
        a = a < 0 ? -a : a;
        v = a > v ? a : v;
      }
      im[ct][r] = v;
    }
#pragma unroll
  for (int o = 1; o < 16; o <<= 1)
#pragma unroll
    for (int ct = 0; ct < 2; ++ct)
#pragma unroll
      for (int r = 0; r < 4; ++r) {
        const int other = __shfl_xor(im[ct][r], o);
        im[ct][r] = other > im[ct][r] ? other : im[ct][r];
      }
  if (m == 0) {
#pragma unroll
    for (int ct = 0; ct < 2; ++ct)
#pragma unroll
      for (int r = 0; r < 4; ++r)
        comax[w * 32 + ct * 16 + g * 4 + r] = (float)im[ct][r];
  }
  __syncthreads();
  float v = 0.f;
  if (t < 128) v = comax[t] * (sf1 * wsf[t]);
  for (int o = 32; o > 0; o >>= 1) v = fmaxf(v, __shfl_xor(v, o));
  if ((t & 63) == 0) red2[t >> 6] = v;
  __syncthreads();
  if (t == 0)
    blockmax[blk] = fmaxf(fmaxf(red2[0], red2[1]), fmaxf(red2[2], red2[3]));
}

// ===== k3: sf2 reduce (per-block) + final int8 GEMM + requant + fused pool =====
__global__ __launch_bounds__(256, 3) void k3_final(
    const signed char* __restrict__ xqT, const signed char* __restrict__ wq8,
    const float* __restrict__ wsf, const unsigned int* __restrict__ gmax,
    const float* __restrict__ blockmax, float* __restrict__ out,
    float* __restrict__ outsf2) {
  __shared__ _Float16 q2[128 * 116];  // 29.7 KB
  __shared__ float red2[4];
  const int t = threadIdx.x, w = t >> 6, l = t & 63;
  const int m = l & 15, g = l >> 4;
  const int blk = blockIdx.x;
  const int n = blk / 28, tt = blk - n * 28;
  const float sf1 = __uint_as_float(*gmax) / QMAXF;

  // ---- per-block sf2 reduction over blockmax[3136] (L2-hot) ----
  float bm = 0.f;
  for (int i = t; i < 3136; i += 256) bm = fmaxf(bm, blockmax[i]);
  for (int o = 32; o > 0; o >>= 1) bm = fmaxf(bm, __shfl_xor(bm, o));
  if ((t & 63) == 0) red2[t >> 6] = bm;
  __syncthreads();
  const float sf2 = fmaxf(fmaxf(red2[0], red2[1]), fmaxf(red2[2], red2[3])) / QMAXF;
  if (blk == 0 && t == 0) outsf2[0] = sf2;

  const signed char* __restrict__ xb = xqT + ((long)(n * 3136 + tt * 112)) * 256;

  i32x4 acc[2][7];
#pragma unroll
  for (int ct = 0; ct < 2; ++ct)
#pragma unroll
    for (int ht = 0; ht < 7; ++ht) acc[ct][ht] = (i32x4){0, 0, 0, 0};

#pragma unroll
  for (int ks = 0; ks < 4; ++ks) {
    i32x4 xf[7];
#pragma unroll
    for (int ht = 0; ht < 7; ++ht)
      xf[ht] = *(const i32x4*)(xb + (ht * 16 + m) * 256 + ks * 64 + g * 16);
#pragma unroll
    for (int ct = 0; ct < 2; ++ct) {
      const i32x4 wf = *(const i32x4*)(wq8 + (w * 32 + ct * 16 + m) * 256 + ks * 64 + g * 16);
#pragma unroll
      for (int ht = 0; ht < 7; ++ht)
        acc[ct][ht] = __builtin_amdgcn_mfma_i32_16x16x64_i8(wf, xf[ht], acc[ct][ht], 0, 0, 0);
    }
  }

  float fac[2][4];
#pragma unroll
  for (int ct = 0; ct < 2; ++ct)
#pragma unroll
    for (int r = 0; r < 4; ++r)
      fac[ct][r] = sf1 * wsf[w * 32 + ct * 16 + g * 4 + r];
#pragma unroll
  for (int ct = 0; ct < 2; ++ct)
#pragma unroll
    for (int ht = 0; ht < 7; ++ht)
#pragma unroll
      for (int r = 0; r < 4; ++r) {
        const float y = (float)acc[ct][ht][r] * fac[ct][r];
        const float q = fminf(fmaxf(rintf(y / sf2), -128.f), 127.f);
        q2[(w * 32 + ct * 16 + g * 4 + r) * 116 + ht * 16 + m] = (_Float16)q;
      }
  __syncthreads();
  const long obase = (long)n * 100352 + tt * 28;
  for (int i = t; i < 3584; i += 256) {
    const unsigned co = (unsigned)i / 28u;
    const unsigned wo = (unsigned)i - co * 28u;
    const _Float16* row = q2 + co * 116;
    const float a = (float)row[2 * wo] + (float)row[2 * wo + 1] +
                    (float)row[56 + 2 * wo] + (float)row[56 + 2 * wo + 1];
    out[obase + (long)co * 784 + wo] = rintf(a * 0.25f) * sf2;
  }
}

extern "C" void kernel_launch(void* const* d_in, const int* in_sizes, int n_in,
                              void* d_out, int out_size, void* d_ws, size_t ws_size,
                              hipStream_t stream) {
  const float* x     = (const float*)d_in[0];
  const float* actsf = (const float*)d_in[1];
  const float* bnw   = (const float*)d_in[2];
  const float* bnb   = (const float*)d_in[3];
  const float* bnm   = (const float*)d_in[4];
  const float* bnv   = (const float*)d_in[5];
  const float* cw    = (const float*)d_in[6];
  float* out = (float*)d_out;
  char* ws = (char*)d_ws;

  unsigned int* gmax  = (unsigned int*)ws;                 // 4 B
  float* scq          = (float*)(ws + 1024);               // 256 f32
  float* shq          = (float*)(ws + 2048);               // 256 f32
  float* wsf          = (float*)(ws + 3072);               // 128 f32
  signed char* wq8    = (signed char*)(ws + 4096);         // 32 KB
  float* blockmax     = (float*)(ws + 36864);              // 3136 f32 (12.5 KB)
  signed char* xqT    = (signed char*)(ws + 65536);        // 51.4 MB (N,HW,C int8)

  hipLaunchKernelGGL(k0_prep, dim3(1), dim3(256), 0, stream,
                     actsf, bnw, bnb, bnm, bnv, cw, wsf, scq, shq, wq8, gmax);
  hipLaunchKernelGGL(k1_max, dim3(2048), dim3(256), 0, stream, x, scq, shq, gmax);
  hipLaunchKernelGGL(k2f_quant_gemm, dim3(3136), dim3(256), 0, stream,
                     x, scq, shq, gmax, wq8, wsf, xqT, blockmax);
  hipLaunchKernelGGL(k3_final, dim3(1792), dim3(256), 0, stream,
                     xqT, wq8, wsf, gmax, blockmax, out, out + (out_size - 1));
}